// Round 6
// baseline (208.950 us; speedup 1.0000x reference)
//
#include <hip/hip_runtime.h>
#include <hip/hip_bf16.h>

// B=2, S=2048, D=1024, H=16, DH=64. fp32 in/out; bf16 MFMA internals.
#define S_LEN   2048
#define D_MODEL 1024
#define N_HEADS 16
#define D_HEAD  64
#define HEAD_ELEMS (2048ull * 64ull)          // elements per (b,h) plane
#define MAT_ELEMS  (4096ull * 1024ull)        // one projected matrix (Q/K/V)
#define W_ELEMS    (1024ull * 1024ull)        // one weight matrix

typedef __attribute__((ext_vector_type(8))) short short8_t;   // 8 bf16
typedef __attribute__((ext_vector_type(4))) short short4_t;   // 4 bf16
typedef __attribute__((ext_vector_type(4))) float f32x4;      // MFMA C/D frag

__device__ __forceinline__ short f2bf(float f) {
    __hip_bfloat16 h = __float2bfloat16(f);
    union { __hip_bfloat16 h; short s; } cv;
    cv.h = h;
    return cv.s;
}

// global_load_lds width=16: LDS dest = wave-uniform base + lane*16
#define GLD_LDS16(gptr, lptr) \
    __builtin_amdgcn_global_load_lds( \
        (const __attribute__((address_space(1))) unsigned int*)(gptr), \
        (__attribute__((address_space(3))) unsigned int*)(lptr), 16, 0, 0)

// ---------------------------------------------------------------------------
// Kernel 0a: convert x fp32 -> bf16.
// ---------------------------------------------------------------------------
__global__ __launch_bounds__(256) void convert_x_kernel(
    const float* __restrict__ x, short* __restrict__ xb)
{
    const int i = (blockIdx.x * 256 + threadIdx.x) * 8;
    const float4 v0 = *(const float4*)(x + i);
    const float4 v1 = *(const float4*)(x + i + 4);
    short8_t u;
    u[0] = f2bf(v0.x); u[1] = f2bf(v0.y); u[2] = f2bf(v0.z); u[3] = f2bf(v0.w);
    u[4] = f2bf(v1.x); u[5] = f2bf(v1.y); u[6] = f2bf(v1.z); u[7] = f2bf(v1.w);
    *(short8_t*)(xb + i) = u;
}

// ---------------------------------------------------------------------------
// Kernel 0b: convert + transpose W fp32[k][n] -> bf16 Wt[n][k].
// ---------------------------------------------------------------------------
__global__ __launch_bounds__(256) void transpose_w_kernel(
    const float* __restrict__ Wq, const float* __restrict__ Wk,
    const float* __restrict__ Wv, short* __restrict__ wt)
{
    const int k0 = blockIdx.x * 64;
    const int n0 = blockIdx.y * 64;
    const int which = blockIdx.z;
    const float* W = (which == 0) ? Wq : (which == 1) ? Wk : Wv;
    short* out = wt + (size_t)which * W_ELEMS;

    __shared__ float Ts[64][68];   // [n_local][k_local]
    const int t = threadIdx.x;
    {
        const int c4 = (t & 15) * 4;
#pragma unroll
        for (int i = 0; i < 4; ++i) {
            const int r = (t >> 4) + i * 16;
            const float4 v = *(const float4*)(W + (size_t)(k0 + r) * D_MODEL + n0 + c4);
            Ts[c4 + 0][r] = v.x; Ts[c4 + 1][r] = v.y;
            Ts[c4 + 2][r] = v.z; Ts[c4 + 3][r] = v.w;
        }
    }
    __syncthreads();
    const int nl = t >> 2;
#pragma unroll
    for (int s = 0; s < 2; ++s) {
        const int koff = (t & 3) * 8 + s * 32;
        short8_t u;
#pragma unroll
        for (int j = 0; j < 8; ++j) u[j] = f2bf(Ts[nl][koff + j]);
        *(short8_t*)(out + (size_t)(n0 + nl) * D_MODEL + k0 + koff) = u;
    }
}

// ---------------------------------------------------------------------------
// Kernel 1: QKV GEMM, m97 structure. For Q/K the MFMA operands are SWAPPED
// (computes C^T) so the C-frag regs run along dh -> 16x 8B stores instead of
// 64x 2B scalar stores. V unswapped (regs run along s, stored (b,h,dh,s)).
// ---------------------------------------------------------------------------
__global__ __launch_bounds__(256, 3) void qkv_mfma_gemm_kernel(
    const short* __restrict__ xb,
    const short* __restrict__ wt,
    short* __restrict__ qkv)
{
    const int mBlock = blockIdx.x * 128;
    const int nBlock = blockIdx.y * 128;
    const int which  = blockIdx.z;
    const short* Bt = wt + (size_t)which * W_ELEMS;
    short* outBase  = qkv + (size_t)which * MAT_ELEMS;

    __shared__ short As[128 * 32];   // [m][k] contiguous, 8 KB
    __shared__ short Bs[128 * 32];   // [n][k] contiguous, 8 KB

    const int t    = threadIdx.x;
    const int w    = t >> 6;
    const int lane = t & 63;
    const int n16  = lane & 15;
    const int quad = lane >> 4;
    const int mq   = (w & 1) * 64;
    const int nq   = (w >> 1) * 64;

    f32x4 acc[4][4];
#pragma unroll
    for (int i = 0; i < 4; ++i)
#pragma unroll
        for (int j = 0; j < 4; ++j) acc[i][j] = (f32x4){0.f, 0.f, 0.f, 0.f};

    const int off0 = w * 2048 + lane * 16;       // bytes
    const int off1 = off0 + 1024;
    const int r0s = off0 >> 6, k0s = (off0 & 63) >> 1;
    const int r1s = off1 >> 6, k1s = (off1 & 63) >> 1;
    const short* gA0 = xb + (size_t)(mBlock + r0s) * D_MODEL + k0s;
    const short* gA1 = xb + (size_t)(mBlock + r1s) * D_MODEL + k1s;
    const short* gB0 = Bt + (size_t)(nBlock + r0s) * D_MODEL + k0s;
    const short* gB1 = Bt + (size_t)(nBlock + r1s) * D_MODEL + k1s;
    short* lA0 = As + w * 1024;
    short* lA1 = As + w * 1024 + 512;
    short* lB0 = Bs + w * 1024;
    short* lB1 = Bs + w * 1024 + 512;

    const bool swapOp = (which < 2);
    for (int k0 = 0; k0 < D_MODEL; k0 += 32) {
        __syncthreads();
        GLD_LDS16(gA0 + k0, lA0);
        GLD_LDS16(gA1 + k0, lA1);
        GLD_LDS16(gB0 + k0, lB0);
        GLD_LDS16(gB1 + k0, lB1);
        __syncthreads();

        short8_t af[4], bf[4];
#pragma unroll
        for (int mt = 0; mt < 4; ++mt)
            af[mt] = *(const short8_t*)&As[(mq + mt * 16 + n16) * 32 + quad * 8];
#pragma unroll
        for (int nt = 0; nt < 4; ++nt)
            bf[nt] = *(const short8_t*)&Bs[(nq + nt * 16 + n16) * 32 + quad * 8];
        if (swapOp) {
#pragma unroll
            for (int mt = 0; mt < 4; ++mt)
#pragma unroll
                for (int nt = 0; nt < 4; ++nt)
                    acc[mt][nt] = __builtin_amdgcn_mfma_f32_16x16x32_bf16(
                        bf[nt], af[mt], acc[mt][nt], 0, 0, 0);
        } else {
#pragma unroll
            for (int mt = 0; mt < 4; ++mt)
#pragma unroll
                for (int nt = 0; nt < 4; ++nt)
                    acc[mt][nt] = __builtin_amdgcn_mfma_f32_16x16x32_bf16(
                        af[mt], bf[nt], acc[mt][nt], 0, 0, 0);
        }
    }

    if (which < 2) {
        // C^T frag: row(quad*4+reg) = n (dh), col(n16) = m (s).
        const float oscale = (which == 0) ? 0.125f : 1.0f;   // 1/sqrt(DH) into Q
#pragma unroll
        for (int nt = 0; nt < 4; ++nt) {
            const int nBase = nBlock + nq + nt * 16 + quad * 4;
            const int h = nBase >> 6, dh0 = nBase & 63;
#pragma unroll
            for (int mt = 0; mt < 4; ++mt) {
                const int mrow = mBlock + mq + mt * 16 + n16;   // s
                const int bb = mrow >> 11, ss = mrow & 2047;
                short4_t u;
                u[0] = f2bf(acc[mt][nt][0] * oscale);
                u[1] = f2bf(acc[mt][nt][1] * oscale);
                u[2] = f2bf(acc[mt][nt][2] * oscale);
                u[3] = f2bf(acc[mt][nt][3] * oscale);
                *(short4_t*)(outBase +
                    ((size_t)(bb * N_HEADS + h) * S_LEN + ss) * D_HEAD + dh0) = u;
            }
        }
    } else {
        // V transposed (b,h,dh,s): regs = 4 consecutive s -> one 8B store
#pragma unroll
        for (int mt = 0; mt < 4; ++mt) {
            const int m0 = mBlock + mq + mt * 16 + quad * 4;
            const int bb = m0 >> 11, ss0 = m0 & 2047;
#pragma unroll
            for (int nt = 0; nt < 4; ++nt) {
                const int n = nBlock + nq + nt * 16 + n16;
                const int h = n >> 6, dh = n & 63;
                short4_t u;
                u[0] = f2bf(acc[mt][nt][0]); u[1] = f2bf(acc[mt][nt][1]);
                u[2] = f2bf(acc[mt][nt][2]); u[3] = f2bf(acc[mt][nt][3]);
                *(short4_t*)(outBase +
                    ((size_t)((bb * N_HEADS + h) * D_HEAD + dh)) * S_LEN + ss0) = u;
            }
        }
    }
}

// ---------------------------------------------------------------------------
// Kernel 2: causal flash attention via bf16 MFMA, v4.
// grid (bh=32, qb=32) -> 1024 blocks, 4 blocks/CU co-resident
// (__launch_bounds__(256,4); LDS 25.6KB x4 = 102KB). Swizzled async staging,
// diagonal-only masking, truncation P-pack (unchanged from v3).
// ---------------------------------------------------------------------------
__global__ __launch_bounds__(256, 4) void attn_mfma_kernel(
    const short* __restrict__ qkv,
    float* __restrict__ out)
{
    const int bh   = blockIdx.x;          // fastest: spreads qb across CUs
    const int qb   = blockIdx.y;
    const int t    = threadIdx.x;
    const int w    = t >> 6;
    const int lane = t & 63;
    const int n    = lane & 15;
    const int quad = lane >> 4;

    const short* Q  = qkv + (size_t)bh * HEAD_ELEMS;
    const short* K  = qkv + MAT_ELEMS + (size_t)bh * HEAD_ELEMS;
    const short* Vt = qkv + 2 * MAT_ELEMS + (size_t)bh * HEAD_ELEMS;  // (dh,s)

    __shared__ __align__(16) short Ks[64 * 64];          // swizzled [row][chunk]
    __shared__ __align__(16) short Vs[64 * 64];          // swizzled [dh][chunk]
    __shared__ __align__(16) short Ps[4][16][72];        // per-wave P round-trip

    // --- staging: wave w stages rows [16w,16w+16) of K and V, 2 insts each ---
    const int srow0 = w * 16 + (lane >> 3);
    const int srow1 = srow0 + 8;
    const int sd0 = ((lane & 7) ^ (srow0 & 7)) * 8;      // swizzled src offset
    const int sd1 = ((lane & 7) ^ (srow1 & 7)) * 8;
    const short* gK0 = K + srow0 * 64 + sd0;
    const short* gK1 = K + srow1 * 64 + sd1;
    const short* gV0 = Vt + (size_t)srow0 * S_LEN + sd0;
    const short* gV1 = Vt + (size_t)srow1 * S_LEN + sd1;
    short* lK0 = Ks + (w * 16) * 64;
    short* lK1 = Ks + (w * 16 + 8) * 64;
    short* lV0 = Vs + (w * 16) * 64;
    short* lV1 = Vs + (w * 16 + 8) * 64;

    // frag-read physical chunk offset (shorts): a0 at pcK, a1 at pcK^32
    const int pcK = (quad ^ (n & 7)) * 8;

    const int bb = bh >> 4;
    const int hh = bh & 15;

    const int r0 = qb * 64 + w * 16;
    const int qrow = r0 + n;

    const short8_t bq0 = *(const short8_t*)(Q + (size_t)qrow * D_HEAD + quad * 8);
    const short8_t bq1 = *(const short8_t*)(Q + (size_t)qrow * D_HEAD + quad * 8 + 32);

    float m = -__builtin_inff();
    float l = 0.f;
    f32x4 o[4];
#pragma unroll
    for (int f = 0; f < 4; ++f) o[f] = (f32x4){0.f, 0.f, 0.f, 0.f};

    for (int tile = 0; tile <= qb; ++tile) {
        const int j0 = tile * 64;
        __syncthreads();                       // prior LDS reads done
        GLD_LDS16(gK0 + j0 * 64, lK0);
        GLD_LDS16(gK1 + j0 * 64, lK1);
        GLD_LDS16(gV0 + j0, lV0);
        GLD_LDS16(gV1 + j0, lV1);
        __syncthreads();                       // vmcnt drained by barrier

        // ---- S^T = K_tile . Q^T (Q pre-scaled by 1/8) ----
        f32x4 st[4];
#pragma unroll
        for (int kg = 0; kg < 4; ++kg) {
            const int rbase = (kg * 16 + n) * 64;
            const short8_t a0 = *(const short8_t*)&Ks[rbase + pcK];
            const short8_t a1 = *(const short8_t*)&Ks[rbase + (pcK ^ 32)];
            f32x4 acc = (f32x4){0.f, 0.f, 0.f, 0.f};
            acc = __builtin_amdgcn_mfma_f32_16x16x32_bf16(a0, bq0, acc, 0, 0, 0);
            acc = __builtin_amdgcn_mfma_f32_16x16x32_bf16(a1, bq1, acc, 0, 0, 0);
            st[kg] = acc;
        }

        // ---- online softmax (mask only on diagonal tile) ----
        float p[16];
        float mx = -__builtin_inff();
        if (tile == qb) {
#pragma unroll
            for (int kg = 0; kg < 4; ++kg)
#pragma unroll
                for (int r = 0; r < 4; ++r) {
                    const int key = j0 + kg * 16 + quad * 4 + r;
                    float s = st[kg][r];
                    s = (key <= qrow) ? s : -__builtin_inff();
                    p[kg * 4 + r] = s;
                    mx = fmaxf(mx, s);
                }
        } else {
#pragma unroll
            for (int i = 0; i < 16; ++i) {
                const float s = st[i >> 2][i & 3];
                p[i] = s;
                mx = fmaxf(mx, s);
            }
        }
        mx = fmaxf(mx, __shfl_xor(mx, 16));
        mx = fmaxf(mx, __shfl_xor(mx, 32));
        const float mnew  = fmaxf(m, mx);
        const float alpha = __expf(m - mnew);
        float ls = 0.f;
#pragma unroll
        for (int i = 0; i < 16; ++i) {
            p[i] = __expf(p[i] - mnew);
            ls += p[i];
        }
        ls += __shfl_xor(ls, 16);
        ls += __shfl_xor(ls, 32);
        l = l * alpha + ls;
        m = mnew;
#pragma unroll
        for (int f = 0; f < 4; ++f) {
            o[f][0] *= alpha; o[f][1] *= alpha; o[f][2] *= alpha; o[f][3] *= alpha;
        }

        // ---- pack P -> bf16 by truncation, same-wave LDS round trip ----
#pragma unroll
        for (int kg = 0; kg < 4; ++kg) {
            const unsigned int b0 = __builtin_bit_cast(unsigned int, p[kg * 4 + 0]);
            const unsigned int b1 = __builtin_bit_cast(unsigned int, p[kg * 4 + 1]);
            const unsigned int b2 = __builtin_bit_cast(unsigned int, p[kg * 4 + 2]);
            const unsigned int b3 = __builtin_bit_cast(unsigned int, p[kg * 4 + 3]);
            uint2 pk;
            pk.x = (b0 >> 16) | (b1 & 0xffff0000u);
            pk.y = (b2 >> 16) | (b3 & 0xffff0000u);
            *(uint2*)&Ps[w][n][kg * 16 + quad * 4] = pk;
        }
        const short8_t pb0 = *(const short8_t*)&Ps[w][n][quad * 8];
        const short8_t pb1 = *(const short8_t*)&Ps[w][n][quad * 8 + 32];

        // ---- O^T += V^T_tile . P^T ----
#pragma unroll
        for (int f = 0; f < 4; ++f) {
            const int rbase = (f * 16 + n) * 64;
            const short8_t va0 = *(const short8_t*)&Vs[rbase + pcK];
            const short8_t va1 = *(const short8_t*)&Vs[rbase + (pcK ^ 32)];
            o[f] = __builtin_amdgcn_mfma_f32_16x16x32_bf16(va0, pb0, o[f], 0, 0, 0);
            o[f] = __builtin_amdgcn_mfma_f32_16x16x32_bf16(va1, pb1, o[f], 0, 0, 0);
        }
    }

    // ---- epilogue: swizzled transpose through Ks/Vs, coalesced stores ----
    __syncthreads();   // all waves done reading Ks/Vs
    float* Os = (float*)((w < 2) ? Ks : Vs) + (w & 1) * 1024;  // 16 rows x 64 f
    const float inv_l = 1.0f / l;
#pragma unroll
    for (int f = 0; f < 4; ++f) {
        const int c  = f * 4 + quad;          // logical 16B chunk (dh/4)
        const int pc = c ^ n;                 // physical chunk
        f32x4 q4;
        q4[0] = o[f][0] * inv_l; q4[1] = o[f][1] * inv_l;
        q4[2] = o[f][2] * inv_l; q4[3] = o[f][3] * inv_l;
        *(f32x4*)&Os[n * 64 + pc * 4] = q4;   // row n, dh chunk c
    }
#pragma unroll
    for (int rr = 0; rr < 4; ++rr) {
        const int row = rr * 4 + quad;        // q-row within wave tile
        const int pc  = n ^ row;              // logical chunk n, swizzled
        const f32x4 val = *(const f32x4*)&Os[row * 64 + pc * 4];
        *(f32x4*)(out + ((size_t)(bb * S_LEN + r0 + row)) * D_MODEL
                      + hh * D_HEAD + n * 4) = val;
    }
}

// ---------------------------------------------------------------------------
extern "C" void kernel_launch(void* const* d_in, const int* in_sizes, int n_in,
                              void* d_out, int out_size, void* d_ws, size_t ws_size,
                              hipStream_t stream) {
    const float* x  = (const float*)d_in[0];
    const float* Wq = (const float*)d_in[1];
    const float* Wk = (const float*)d_in[2];
    const float* Wv = (const float*)d_in[3];
    float* out = (float*)d_out;

    // workspace: xb (8MB) | wt (6MB) | qkv (24MB) = 38MB
    short* xb  = (short*)d_ws;
    short* wt  = xb + MAT_ELEMS;
    short* qkv = wt + 3 * W_ELEMS;

    convert_x_kernel<<<dim3(MAT_ELEMS / (256 * 8)), 256, 0, stream>>>(x, xb);
    transpose_w_kernel<<<dim3(16, 16, 3), 256, 0, stream>>>(Wq, Wk, Wv, wt);

    qkv_mfma_gemm_kernel<<<dim3(32, 8, 3), 256, 0, stream>>>(xb, wt, qkv);

    attn_mfma_kernel<<<dim3(2 * N_HEADS, S_LEN / 64), 256, 0, stream>>>(qkv, out);
}

// Round 7
// 166.980 us; speedup vs baseline: 1.2513x; 1.2513x over previous
//
#include <hip/hip_runtime.h>
#include <hip/hip_bf16.h>

// B=2, S=2048, D=1024, H=16, DH=64. fp32 in/out; bf16 MFMA internals.
#define S_LEN   2048
#define D_MODEL 1024
#define N_HEADS 16
#define D_HEAD  64
#define HEAD_ELEMS (2048ull * 64ull)          // elements per (b,h) plane
#define MAT_ELEMS  (4096ull * 1024ull)        // one projected matrix (Q/K/V)
#define W_ELEMS    (1024ull * 1024ull)        // one weight matrix

typedef __attribute__((ext_vector_type(8))) short short8_t;   // 8 bf16
typedef __attribute__((ext_vector_type(4))) short short4_t;   // 4 bf16
typedef __attribute__((ext_vector_type(4))) float f32x4;      // MFMA C/D frag

__device__ __forceinline__ short f2bf(float f) {
    __hip_bfloat16 h = __float2bfloat16(f);
    union { __hip_bfloat16 h; short s; } cv;
    cv.h = h;
    return cv.s;
}

// global_load_lds width=16: LDS dest = wave-uniform base + lane*16
#define GLD_LDS16(gptr, lptr) \
    __builtin_amdgcn_global_load_lds( \
        (const __attribute__((address_space(1))) unsigned int*)(gptr), \
        (__attribute__((address_space(3))) unsigned int*)(lptr), 16, 0, 0)

// ---------------------------------------------------------------------------
// Kernel 0a: convert x fp32 -> bf16.
// ---------------------------------------------------------------------------
__global__ __launch_bounds__(256) void convert_x_kernel(
    const float* __restrict__ x, short* __restrict__ xb)
{
    const int i = (blockIdx.x * 256 + threadIdx.x) * 8;
    const float4 v0 = *(const float4*)(x + i);
    const float4 v1 = *(const float4*)(x + i + 4);
    short8_t u;
    u[0] = f2bf(v0.x); u[1] = f2bf(v0.y); u[2] = f2bf(v0.z); u[3] = f2bf(v0.w);
    u[4] = f2bf(v1.x); u[5] = f2bf(v1.y); u[6] = f2bf(v1.z); u[7] = f2bf(v1.w);
    *(short8_t*)(xb + i) = u;
}

// ---------------------------------------------------------------------------
// Kernel 0b: convert + transpose W fp32[k][n] -> bf16 Wt[n][k].
// ---------------------------------------------------------------------------
__global__ __launch_bounds__(256) void transpose_w_kernel(
    const float* __restrict__ Wq, const float* __restrict__ Wk,
    const float* __restrict__ Wv, short* __restrict__ wt)
{
    const int k0 = blockIdx.x * 64;
    const int n0 = blockIdx.y * 64;
    const int which = blockIdx.z;
    const float* W = (which == 0) ? Wq : (which == 1) ? Wk : Wv;
    short* out = wt + (size_t)which * W_ELEMS;

    __shared__ float Ts[64][68];   // [n_local][k_local]
    const int t = threadIdx.x;
    {
        const int c4 = (t & 15) * 4;
#pragma unroll
        for (int i = 0; i < 4; ++i) {
            const int r = (t >> 4) + i * 16;
            const float4 v = *(const float4*)(W + (size_t)(k0 + r) * D_MODEL + n0 + c4);
            Ts[c4 + 0][r] = v.x; Ts[c4 + 1][r] = v.y;
            Ts[c4 + 2][r] = v.z; Ts[c4 + 3][r] = v.w;
        }
    }
    __syncthreads();
    const int nl = t >> 2;
#pragma unroll
    for (int s = 0; s < 2; ++s) {
        const int koff = (t & 3) * 8 + s * 32;
        short8_t u;
#pragma unroll
        for (int j = 0; j < 8; ++j) u[j] = f2bf(Ts[nl][koff + j]);
        *(short8_t*)(out + (size_t)(n0 + nl) * D_MODEL + k0 + koff) = u;
    }
}

// ---------------------------------------------------------------------------
// Kernel 1: QKV GEMM, m97 structure (round-5 epilogue: 2B stores are
// contiguous across the 16 lanes of a quad -> 32B runs; the round-6 swapped
// variant scattered 8B stores at 128B stride and blew WRITE_SIZE 7x).
// Q epilogue folds 1/sqrt(DH) * log2(e) so attention can use exp2f.
// ---------------------------------------------------------------------------
__global__ __launch_bounds__(256, 3) void qkv_mfma_gemm_kernel(
    const short* __restrict__ xb,
    const short* __restrict__ wt,
    short* __restrict__ qkv)
{
    const int mBlock = blockIdx.x * 128;
    const int nBlock = blockIdx.y * 128;
    const int which  = blockIdx.z;
    const short* Bt = wt + (size_t)which * W_ELEMS;
    short* outBase  = qkv + (size_t)which * MAT_ELEMS;

    __shared__ short As[128 * 32];   // [m][k] contiguous, 8 KB
    __shared__ short Bs[128 * 32];   // [n][k] contiguous, 8 KB

    const int t    = threadIdx.x;
    const int w    = t >> 6;
    const int lane = t & 63;
    const int n16  = lane & 15;
    const int quad = lane >> 4;
    const int mq   = (w & 1) * 64;
    const int nq   = (w >> 1) * 64;

    f32x4 acc[4][4];
#pragma unroll
    for (int i = 0; i < 4; ++i)
#pragma unroll
        for (int j = 0; j < 4; ++j) acc[i][j] = (f32x4){0.f, 0.f, 0.f, 0.f};

    const int off0 = w * 2048 + lane * 16;       // bytes
    const int off1 = off0 + 1024;
    const int r0s = off0 >> 6, k0s = (off0 & 63) >> 1;
    const int r1s = off1 >> 6, k1s = (off1 & 63) >> 1;
    const short* gA0 = xb + (size_t)(mBlock + r0s) * D_MODEL + k0s;
    const short* gA1 = xb + (size_t)(mBlock + r1s) * D_MODEL + k1s;
    const short* gB0 = Bt + (size_t)(nBlock + r0s) * D_MODEL + k0s;
    const short* gB1 = Bt + (size_t)(nBlock + r1s) * D_MODEL + k1s;
    short* lA0 = As + w * 1024;
    short* lA1 = As + w * 1024 + 512;
    short* lB0 = Bs + w * 1024;
    short* lB1 = Bs + w * 1024 + 512;

    for (int k0 = 0; k0 < D_MODEL; k0 += 32) {
        __syncthreads();
        GLD_LDS16(gA0 + k0, lA0);
        GLD_LDS16(gA1 + k0, lA1);
        GLD_LDS16(gB0 + k0, lB0);
        GLD_LDS16(gB1 + k0, lB1);
        __syncthreads();

        short8_t af[4], bf[4];
#pragma unroll
        for (int mt = 0; mt < 4; ++mt)
            af[mt] = *(const short8_t*)&As[(mq + mt * 16 + n16) * 32 + quad * 8];
#pragma unroll
        for (int nt = 0; nt < 4; ++nt)
            bf[nt] = *(const short8_t*)&Bs[(nq + nt * 16 + n16) * 32 + quad * 8];
#pragma unroll
        for (int mt = 0; mt < 4; ++mt)
#pragma unroll
            for (int nt = 0; nt < 4; ++nt)
                acc[mt][nt] = __builtin_amdgcn_mfma_f32_16x16x32_bf16(
                    af[mt], bf[nt], acc[mt][nt], 0, 0, 0);
    }

    // Q scale: 1/sqrt(64) * log2(e) so softmax uses exp2f directly.
    const float oscale = (which == 0) ? 0.18033688f : 1.0f;
    if (which < 2) {
#pragma unroll
        for (int mt = 0; mt < 4; ++mt) {
#pragma unroll
            for (int nt = 0; nt < 4; ++nt) {
                const int n = nBlock + nq + nt * 16 + n16;
                const int h = n >> 6, dh = n & 63;
#pragma unroll
                for (int reg = 0; reg < 4; ++reg) {
                    const int m = mBlock + mq + mt * 16 + quad * 4 + reg;
                    const int bb = m >> 11, ss = m & 2047;
                    outBase[((size_t)(bb * N_HEADS + h) * S_LEN + ss) * D_HEAD + dh] =
                        f2bf(acc[mt][nt][reg] * oscale);
                }
            }
        }
    } else {
        // V transposed (b,h,dh,s): regs = 4 consecutive s -> one 8B store
#pragma unroll
        for (int mt = 0; mt < 4; ++mt) {
            const int m0 = mBlock + mq + mt * 16 + quad * 4;
            const int bb = m0 >> 11, ss0 = m0 & 2047;
#pragma unroll
            for (int nt = 0; nt < 4; ++nt) {
                const int n = nBlock + nq + nt * 16 + n16;
                const int h = n >> 6, dh = n & 63;
                short4_t u;
                u[0] = f2bf(acc[mt][nt][0]); u[1] = f2bf(acc[mt][nt][1]);
                u[2] = f2bf(acc[mt][nt][2]); u[3] = f2bf(acc[mt][nt][3]);
                *(short4_t*)(outBase +
                    ((size_t)((bb * N_HEADS + h) * D_HEAD + dh)) * S_LEN + ss0) = u;
            }
        }
    }
}

// ---------------------------------------------------------------------------
// Kernel 2: causal flash attention via bf16 MFMA, v5.
// Flat grid 1024, qb = ((id&3)^((id>>8)&3))*8 + ((id>>2)&7), bh = (id>>5)&31:
// balanced per-CU work (qb set {t,t+8,t+16,t+24}) under BOTH chunked and
// stride-256 round-robin block->CU mappings, with 4 blocks/CU co-resident.
// Softmax in exp2 domain (log2e folded into Q by the GEMM).
// ---------------------------------------------------------------------------
__global__ __launch_bounds__(256, 4) void attn_mfma_kernel(
    const short* __restrict__ qkv,
    float* __restrict__ out)
{
    const int id   = blockIdx.x;
    const int qb   = (((id & 3) ^ ((id >> 8) & 3)) << 3) | ((id >> 2) & 7);
    const int bh   = (id >> 5) & 31;
    const int t    = threadIdx.x;
    const int w    = t >> 6;
    const int lane = t & 63;
    const int n    = lane & 15;
    const int quad = lane >> 4;

    const short* Q  = qkv + (size_t)bh * HEAD_ELEMS;
    const short* K  = qkv + MAT_ELEMS + (size_t)bh * HEAD_ELEMS;
    const short* Vt = qkv + 2 * MAT_ELEMS + (size_t)bh * HEAD_ELEMS;  // (dh,s)

    __shared__ __align__(16) short Ks[64 * 64];          // swizzled [row][chunk]
    __shared__ __align__(16) short Vs[64 * 64];          // swizzled [dh][chunk]
    __shared__ __align__(16) short Ps[4][16][72];        // per-wave P round-trip

    // --- staging: wave w stages rows [16w,16w+16) of K and V, 2 insts each ---
    const int srow0 = w * 16 + (lane >> 3);
    const int srow1 = srow0 + 8;
    const int sd0 = ((lane & 7) ^ (srow0 & 7)) * 8;      // swizzled src offset
    const int sd1 = ((lane & 7) ^ (srow1 & 7)) * 8;
    const short* gK0 = K + srow0 * 64 + sd0;
    const short* gK1 = K + srow1 * 64 + sd1;
    const short* gV0 = Vt + (size_t)srow0 * S_LEN + sd0;
    const short* gV1 = Vt + (size_t)srow1 * S_LEN + sd1;
    short* lK0 = Ks + (w * 16) * 64;
    short* lK1 = Ks + (w * 16 + 8) * 64;
    short* lV0 = Vs + (w * 16) * 64;
    short* lV1 = Vs + (w * 16 + 8) * 64;

    // frag-read physical chunk offset (shorts): a0 at pcK, a1 at pcK^32
    const int pcK = (quad ^ (n & 7)) * 8;

    const int bb = bh >> 4;
    const int hh = bh & 15;

    const int r0 = qb * 64 + w * 16;
    const int qrow = r0 + n;

    const short8_t bq0 = *(const short8_t*)(Q + (size_t)qrow * D_HEAD + quad * 8);
    const short8_t bq1 = *(const short8_t*)(Q + (size_t)qrow * D_HEAD + quad * 8 + 32);

    float m = -__builtin_inff();
    float l = 0.f;
    f32x4 o[4];
#pragma unroll
    for (int f = 0; f < 4; ++f) o[f] = (f32x4){0.f, 0.f, 0.f, 0.f};

    for (int tile = 0; tile <= qb; ++tile) {
        const int j0 = tile * 64;
        __syncthreads();                       // prior LDS reads done
        GLD_LDS16(gK0 + j0 * 64, lK0);
        GLD_LDS16(gK1 + j0 * 64, lK1);
        GLD_LDS16(gV0 + j0, lV0);
        GLD_LDS16(gV1 + j0, lV1);
        __syncthreads();                       // vmcnt drained by barrier

        // ---- S^T = K_tile . Q^T (Q pre-scaled by 0.125*log2e) ----
        f32x4 st[4];
#pragma unroll
        for (int kg = 0; kg < 4; ++kg) {
            const int rbase = (kg * 16 + n) * 64;
            const short8_t a0 = *(const short8_t*)&Ks[rbase + pcK];
            const short8_t a1 = *(const short8_t*)&Ks[rbase + (pcK ^ 32)];
            f32x4 acc = (f32x4){0.f, 0.f, 0.f, 0.f};
            acc = __builtin_amdgcn_mfma_f32_16x16x32_bf16(a0, bq0, acc, 0, 0, 0);
            acc = __builtin_amdgcn_mfma_f32_16x16x32_bf16(a1, bq1, acc, 0, 0, 0);
            st[kg] = acc;
        }

        // ---- online softmax in exp2 domain (mask only on diagonal tile) ----
        float p[16];
        float mx = -__builtin_inff();
        if (tile == qb) {
#pragma unroll
            for (int kg = 0; kg < 4; ++kg)
#pragma unroll
                for (int r = 0; r < 4; ++r) {
                    const int key = j0 + kg * 16 + quad * 4 + r;
                    float s = st[kg][r];
                    s = (key <= qrow) ? s : -__builtin_inff();
                    p[kg * 4 + r] = s;
                    mx = fmaxf(mx, s);
                }
        } else {
#pragma unroll
            for (int i = 0; i < 16; ++i) {
                const float s = st[i >> 2][i & 3];
                p[i] = s;
                mx = fmaxf(mx, s);
            }
        }
        mx = fmaxf(mx, __shfl_xor(mx, 16));
        mx = fmaxf(mx, __shfl_xor(mx, 32));
        const float mnew  = fmaxf(m, mx);
        const float alpha = exp2f(m - mnew);
        float ls = 0.f;
#pragma unroll
        for (int i = 0; i < 16; ++i) {
            p[i] = exp2f(p[i] - mnew);
            ls += p[i];
        }
        ls += __shfl_xor(ls, 16);
        ls += __shfl_xor(ls, 32);
        l = l * alpha + ls;
        m = mnew;
#pragma unroll
        for (int f = 0; f < 4; ++f) {
            o[f][0] *= alpha; o[f][1] *= alpha; o[f][2] *= alpha; o[f][3] *= alpha;
        }

        // ---- pack P -> bf16 by truncation, same-wave LDS round trip ----
#pragma unroll
        for (int kg = 0; kg < 4; ++kg) {
            const unsigned int b0 = __builtin_bit_cast(unsigned int, p[kg * 4 + 0]);
            const unsigned int b1 = __builtin_bit_cast(unsigned int, p[kg * 4 + 1]);
            const unsigned int b2 = __builtin_bit_cast(unsigned int, p[kg * 4 + 2]);
            const unsigned int b3 = __builtin_bit_cast(unsigned int, p[kg * 4 + 3]);
            uint2 pk;
            pk.x = (b0 >> 16) | (b1 & 0xffff0000u);
            pk.y = (b2 >> 16) | (b3 & 0xffff0000u);
            *(uint2*)&Ps[w][n][kg * 16 + quad * 4] = pk;
        }
        const short8_t pb0 = *(const short8_t*)&Ps[w][n][quad * 8];
        const short8_t pb1 = *(const short8_t*)&Ps[w][n][quad * 8 + 32];

        // ---- O^T += V^T_tile . P^T ----
#pragma unroll
        for (int f = 0; f < 4; ++f) {
            const int rbase = (f * 16 + n) * 64;
            const short8_t va0 = *(const short8_t*)&Vs[rbase + pcK];
            const short8_t va1 = *(const short8_t*)&Vs[rbase + (pcK ^ 32)];
            o[f] = __builtin_amdgcn_mfma_f32_16x16x32_bf16(va0, pb0, o[f], 0, 0, 0);
            o[f] = __builtin_amdgcn_mfma_f32_16x16x32_bf16(va1, pb1, o[f], 0, 0, 0);
        }
    }

    // ---- epilogue: swizzled transpose through Ks/Vs, coalesced stores ----
    __syncthreads();   // all waves done reading Ks/Vs
    float* Os = (float*)((w < 2) ? Ks : Vs) + (w & 1) * 1024;  // 16 rows x 64 f
    const float inv_l = 1.0f / l;
#pragma unroll
    for (int f = 0; f < 4; ++f) {
        const int c  = f * 4 + quad;          // logical 16B chunk (dh/4)
        const int pc = c ^ n;                 // physical chunk
        f32x4 q4;
        q4[0] = o[f][0] * inv_l; q4[1] = o[f][1] * inv_l;
        q4[2] = o[f][2] * inv_l; q4[3] = o[f][3] * inv_l;
        *(f32x4*)&Os[n * 64 + pc * 4] = q4;   // row n, dh chunk c
    }
#pragma unroll
    for (int rr = 0; rr < 4; ++rr) {
        const int row = rr * 4 + quad;        // q-row within wave tile
        const int pc  = n ^ row;              // logical chunk n, swizzled
        const f32x4 val = *(const f32x4*)&Os[row * 64 + pc * 4];
        *(f32x4*)(out + ((size_t)(bb * S_LEN + r0 + row)) * D_MODEL
                      + hh * D_HEAD + n * 4) = val;
    }
}

// ---------------------------------------------------------------------------
extern "C" void kernel_launch(void* const* d_in, const int* in_sizes, int n_in,
                              void* d_out, int out_size, void* d_ws, size_t ws_size,
                              hipStream_t stream) {
    const float* x  = (const float*)d_in[0];
    const float* Wq = (const float*)d_in[1];
    const float* Wk = (const float*)d_in[2];
    const float* Wv = (const float*)d_in[3];
    float* out = (float*)d_out;

    // workspace: xb (8MB) | wt (6MB) | qkv (24MB) = 38MB
    short* xb  = (short*)d_ws;
    short* wt  = xb + MAT_ELEMS;
    short* qkv = wt + 3 * W_ELEMS;

    convert_x_kernel<<<dim3(MAT_ELEMS / (256 * 8)), 256, 0, stream>>>(x, xb);
    transpose_w_kernel<<<dim3(16, 16, 3), 256, 0, stream>>>(Wq, Wk, Wv, wt);

    qkv_mfma_gemm_kernel<<<dim3(32, 8, 3), 256, 0, stream>>>(xb, wt, qkv);

    attn_mfma_kernel<<<dim3(32 * 32), 256, 0, stream>>>(qkv, out);
}

// Round 8
// 160.384 us; speedup vs baseline: 1.3028x; 1.0411x over previous
//
#include <hip/hip_runtime.h>
#include <hip/hip_bf16.h>

// B=2, S=2048, D=1024, H=16, DH=64. fp32 in/out; bf16 MFMA internals.
#define S_LEN   2048
#define D_MODEL 1024
#define N_HEADS 16
#define D_HEAD  64
#define HEAD_ELEMS (2048ull * 64ull)          // elements per (b,h) plane
#define MAT_ELEMS  (4096ull * 1024ull)        // one projected matrix (Q/K/V)
#define W_ELEMS    (1024ull * 1024ull)        // one weight matrix

typedef __attribute__((ext_vector_type(8))) short short8_t;   // 8 bf16
typedef __attribute__((ext_vector_type(4))) short short4_t;   // 4 bf16
typedef __attribute__((ext_vector_type(4))) float f32x4;      // MFMA C/D frag

__device__ __forceinline__ short f2bf(float f) {
    __hip_bfloat16 h = __float2bfloat16(f);
    union { __hip_bfloat16 h; short s; } cv;
    cv.h = h;
    return cv.s;
}

// global_load_lds width=16: LDS dest = wave-uniform base + lane*16
#define GLD_LDS16(gptr, lptr) \
    __builtin_amdgcn_global_load_lds( \
        (const __attribute__((address_space(1))) unsigned int*)(gptr), \
        (__attribute__((address_space(3))) unsigned int*)(lptr), 16, 0, 0)

// ---------------------------------------------------------------------------
// Kernel 0a: convert x fp32 -> bf16.
// ---------------------------------------------------------------------------
__global__ __launch_bounds__(256) void convert_x_kernel(
    const float* __restrict__ x, short* __restrict__ xb)
{
    const int i = (blockIdx.x * 256 + threadIdx.x) * 8;
    const float4 v0 = *(const float4*)(x + i);
    const float4 v1 = *(const float4*)(x + i + 4);
    short8_t u;
    u[0] = f2bf(v0.x); u[1] = f2bf(v0.y); u[2] = f2bf(v0.z); u[3] = f2bf(v0.w);
    u[4] = f2bf(v1.x); u[5] = f2bf(v1.y); u[6] = f2bf(v1.z); u[7] = f2bf(v1.w);
    *(short8_t*)(xb + i) = u;
}

// ---------------------------------------------------------------------------
// Kernel 0b: convert + transpose W fp32[k][n] -> bf16 Wt[n][k].
// ---------------------------------------------------------------------------
__global__ __launch_bounds__(256) void transpose_w_kernel(
    const float* __restrict__ Wq, const float* __restrict__ Wk,
    const float* __restrict__ Wv, short* __restrict__ wt)
{
    const int k0 = blockIdx.x * 64;
    const int n0 = blockIdx.y * 64;
    const int which = blockIdx.z;
    const float* W = (which == 0) ? Wq : (which == 1) ? Wk : Wv;
    short* out = wt + (size_t)which * W_ELEMS;

    __shared__ float Ts[64][68];   // [n_local][k_local]
    const int t = threadIdx.x;
    {
        const int c4 = (t & 15) * 4;
#pragma unroll
        for (int i = 0; i < 4; ++i) {
            const int r = (t >> 4) + i * 16;
            const float4 v = *(const float4*)(W + (size_t)(k0 + r) * D_MODEL + n0 + c4);
            Ts[c4 + 0][r] = v.x; Ts[c4 + 1][r] = v.y;
            Ts[c4 + 2][r] = v.z; Ts[c4 + 3][r] = v.w;
        }
    }
    __syncthreads();
    const int nl = t >> 2;
#pragma unroll
    for (int s = 0; s < 2; ++s) {
        const int koff = (t & 3) * 8 + s * 32;
        short8_t u;
#pragma unroll
        for (int j = 0; j < 8; ++j) u[j] = f2bf(Ts[nl][koff + j]);
        *(short8_t*)(out + (size_t)(n0 + nl) * D_MODEL + k0 + koff) = u;
    }
}

// ---------------------------------------------------------------------------
// Kernel 1: QKV GEMM, m97 structure (round-5 epilogue; Q folds 0.125*log2e).
// ---------------------------------------------------------------------------
__global__ __launch_bounds__(256, 3) void qkv_mfma_gemm_kernel(
    const short* __restrict__ xb,
    const short* __restrict__ wt,
    short* __restrict__ qkv)
{
    const int mBlock = blockIdx.x * 128;
    const int nBlock = blockIdx.y * 128;
    const int which  = blockIdx.z;
    const short* Bt = wt + (size_t)which * W_ELEMS;
    short* outBase  = qkv + (size_t)which * MAT_ELEMS;

    __shared__ short As[128 * 32];   // [m][k] contiguous, 8 KB
    __shared__ short Bs[128 * 32];   // [n][k] contiguous, 8 KB

    const int t    = threadIdx.x;
    const int w    = t >> 6;
    const int lane = t & 63;
    const int n16  = lane & 15;
    const int quad = lane >> 4;
    const int mq   = (w & 1) * 64;
    const int nq   = (w >> 1) * 64;

    f32x4 acc[4][4];
#pragma unroll
    for (int i = 0; i < 4; ++i)
#pragma unroll
        for (int j = 0; j < 4; ++j) acc[i][j] = (f32x4){0.f, 0.f, 0.f, 0.f};

    const int off0 = w * 2048 + lane * 16;       // bytes
    const int off1 = off0 + 1024;
    const int r0s = off0 >> 6, k0s = (off0 & 63) >> 1;
    const int r1s = off1 >> 6, k1s = (off1 & 63) >> 1;
    const short* gA0 = xb + (size_t)(mBlock + r0s) * D_MODEL + k0s;
    const short* gA1 = xb + (size_t)(mBlock + r1s) * D_MODEL + k1s;
    const short* gB0 = Bt + (size_t)(nBlock + r0s) * D_MODEL + k0s;
    const short* gB1 = Bt + (size_t)(nBlock + r1s) * D_MODEL + k1s;
    short* lA0 = As + w * 1024;
    short* lA1 = As + w * 1024 + 512;
    short* lB0 = Bs + w * 1024;
    short* lB1 = Bs + w * 1024 + 512;

    for (int k0 = 0; k0 < D_MODEL; k0 += 32) {
        __syncthreads();
        GLD_LDS16(gA0 + k0, lA0);
        GLD_LDS16(gA1 + k0, lA1);
        GLD_LDS16(gB0 + k0, lB0);
        GLD_LDS16(gB1 + k0, lB1);
        __syncthreads();

        short8_t af[4], bf[4];
#pragma unroll
        for (int mt = 0; mt < 4; ++mt)
            af[mt] = *(const short8_t*)&As[(mq + mt * 16 + n16) * 32 + quad * 8];
#pragma unroll
        for (int nt = 0; nt < 4; ++nt)
            bf[nt] = *(const short8_t*)&Bs[(nq + nt * 16 + n16) * 32 + quad * 8];
#pragma unroll
        for (int mt = 0; mt < 4; ++mt)
#pragma unroll
            for (int nt = 0; nt < 4; ++nt)
                acc[mt][nt] = __builtin_amdgcn_mfma_f32_16x16x32_bf16(
                    af[mt], bf[nt], acc[mt][nt], 0, 0, 0);
    }

    // Q scale: 1/sqrt(64) * log2(e) so softmax uses exp2f directly.
    const float oscale = (which == 0) ? 0.18033688f : 1.0f;
    if (which < 2) {
#pragma unroll
        for (int mt = 0; mt < 4; ++mt) {
#pragma unroll
            for (int nt = 0; nt < 4; ++nt) {
                const int n = nBlock + nq + nt * 16 + n16;
                const int h = n >> 6, dh = n & 63;
#pragma unroll
                for (int reg = 0; reg < 4; ++reg) {
                    const int m = mBlock + mq + mt * 16 + quad * 4 + reg;
                    const int bb = m >> 11, ss = m & 2047;
                    outBase[((size_t)(bb * N_HEADS + h) * S_LEN + ss) * D_HEAD + dh] =
                        f2bf(acc[mt][nt][reg] * oscale);
                }
            }
        }
    } else {
        // V transposed (b,h,dh,s): regs = 4 consecutive s -> one 8B store
#pragma unroll
        for (int mt = 0; mt < 4; ++mt) {
            const int m0 = mBlock + mq + mt * 16 + quad * 4;
            const int bb = m0 >> 11, ss0 = m0 & 2047;
#pragma unroll
            for (int nt = 0; nt < 4; ++nt) {
                const int n = nBlock + nq + nt * 16 + n16;
                const int h = n >> 6, dh = n & 63;
                short4_t u;
                u[0] = f2bf(acc[mt][nt][0]); u[1] = f2bf(acc[mt][nt][1]);
                u[2] = f2bf(acc[mt][nt][2]); u[3] = f2bf(acc[mt][nt][3]);
                *(short4_t*)(outBase +
                    ((size_t)((bb * N_HEADS + h) * D_HEAD + dh)) * S_LEN + ss0) = u;
            }
        }
    }
}

// ---------------------------------------------------------------------------
// Kernel 2: causal flash attention via bf16 MFMA, v6.
// grid (bh=32, pair=16), bh fastest (round-5 L2 locality: FETCH ~12 MB).
// DOUBLE-BUFFERED async staging: iter = {barrier; prefetch tile t+1 into
// other buffer; compute tile t}. The barrier at the top of iter t+1 drains a
// prefetch that got the whole compute phase as head start (legal workaround
// for the vmcnt(0)-at-barrier drain). One barrier per tile.
// ---------------------------------------------------------------------------
__global__ __launch_bounds__(256, 2) void attn_mfma_kernel(
    const short* __restrict__ qkv,
    float* __restrict__ out)
{
    const int bh   = blockIdx.x;
    const int pr   = blockIdx.y;          // pair index 0..15
    const int t    = threadIdx.x;
    const int w    = t >> 6;
    const int lane = t & 63;
    const int n    = lane & 15;
    const int quad = lane >> 4;

    const short* Q  = qkv + (size_t)bh * HEAD_ELEMS;
    const short* K  = qkv + MAT_ELEMS + (size_t)bh * HEAD_ELEMS;
    const short* Vt = qkv + 2 * MAT_ELEMS + (size_t)bh * HEAD_ELEMS;  // (dh,s)

    __shared__ __align__(16) short Ks[2 * 64 * 64];      // dbuf, swizzled
    __shared__ __align__(16) short Vs[2 * 64 * 64];      // dbuf, swizzled
    __shared__ __align__(16) short Ps[4][16][72];        // per-wave P round-trip

    // --- staging: wave w stages rows [16w,16w+16) of K and V, 2 insts each ---
    const int srow0 = w * 16 + (lane >> 3);
    const int srow1 = srow0 + 8;
    const int sd0 = ((lane & 7) ^ (srow0 & 7)) * 8;      // swizzled src offset
    const int sd1 = ((lane & 7) ^ (srow1 & 7)) * 8;
    const short* gK0 = K + srow0 * 64 + sd0;
    const short* gK1 = K + srow1 * 64 + sd1;
    const short* gV0 = Vt + (size_t)srow0 * S_LEN + sd0;
    const short* gV1 = Vt + (size_t)srow1 * S_LEN + sd1;
    short* lK0 = Ks + (w * 16) * 64;
    short* lK1 = Ks + (w * 16 + 8) * 64;
    short* lV0 = Vs + (w * 16) * 64;
    short* lV1 = Vs + (w * 16 + 8) * 64;

    // frag-read physical chunk offset (shorts): a0 at pcK, a1 at pcK^32
    const int pcK = (quad ^ (n & 7)) * 8;

    const int bb = bh >> 4;
    const int hh = bh & 15;

    for (int pass = 0; pass < 2; ++pass) {
        const int qb = pass ? (31 - pr) : pr;
        const int r0 = qb * 64 + w * 16;
        const int qrow = r0 + n;

        const short8_t bq0 = *(const short8_t*)(Q + (size_t)qrow * D_HEAD + quad * 8);
        const short8_t bq1 = *(const short8_t*)(Q + (size_t)qrow * D_HEAD + quad * 8 + 32);

        float m = -__builtin_inff();
        float l = 0.f;
        f32x4 o[4];
#pragma unroll
        for (int f = 0; f < 4; ++f) o[f] = (f32x4){0.f, 0.f, 0.f, 0.f};

        // prologue: guard vs prior pass's epilogue LDS reads, then stage tile 0
        __syncthreads();
        GLD_LDS16(gK0, lK0);
        GLD_LDS16(gK1, lK1);
        GLD_LDS16(gV0, lV0);
        GLD_LDS16(gV1, lV1);

        for (int tile = 0; tile <= qb; ++tile) {
            const int cur = (tile & 1) * 4096;
            __syncthreads();               // publishes buf[cur]; prior reads done

            if (tile < qb) {               // prefetch t+1 into other buffer
                const int nxt = ((tile + 1) & 1) * 4096;
                const int j1 = (tile + 1) * 64;
                GLD_LDS16(gK0 + j1 * 64, lK0 + nxt);
                GLD_LDS16(gK1 + j1 * 64, lK1 + nxt);
                GLD_LDS16(gV0 + j1, lV0 + nxt);
                GLD_LDS16(gV1 + j1, lV1 + nxt);
            }

            const int j0 = tile * 64;

            // ---- S^T = K_tile . Q^T (Q pre-scaled by 0.125*log2e) ----
            f32x4 st[4];
#pragma unroll
            for (int kg = 0; kg < 4; ++kg) {
                const int rbase = cur + (kg * 16 + n) * 64;
                const short8_t a0 = *(const short8_t*)&Ks[rbase + pcK];
                const short8_t a1 = *(const short8_t*)&Ks[rbase + (pcK ^ 32)];
                f32x4 acc = (f32x4){0.f, 0.f, 0.f, 0.f};
                acc = __builtin_amdgcn_mfma_f32_16x16x32_bf16(a0, bq0, acc, 0, 0, 0);
                acc = __builtin_amdgcn_mfma_f32_16x16x32_bf16(a1, bq1, acc, 0, 0, 0);
                st[kg] = acc;
            }

            // ---- online softmax in exp2 domain (mask only on diagonal) ----
            float p[16];
            float mx = -__builtin_inff();
            if (tile == qb) {
#pragma unroll
                for (int kg = 0; kg < 4; ++kg)
#pragma unroll
                    for (int r = 0; r < 4; ++r) {
                        const int key = j0 + kg * 16 + quad * 4 + r;
                        float s = st[kg][r];
                        s = (key <= qrow) ? s : -__builtin_inff();
                        p[kg * 4 + r] = s;
                        mx = fmaxf(mx, s);
                    }
            } else {
#pragma unroll
                for (int i = 0; i < 16; ++i) {
                    const float s = st[i >> 2][i & 3];
                    p[i] = s;
                    mx = fmaxf(mx, s);
                }
            }
            mx = fmaxf(mx, __shfl_xor(mx, 16));
            mx = fmaxf(mx, __shfl_xor(mx, 32));
            const float mnew  = fmaxf(m, mx);
            const float alpha = exp2f(m - mnew);
            float ls = 0.f;
#pragma unroll
            for (int i = 0; i < 16; ++i) {
                p[i] = exp2f(p[i] - mnew);
                ls += p[i];
            }
            ls += __shfl_xor(ls, 16);
            ls += __shfl_xor(ls, 32);
            l = l * alpha + ls;
            m = mnew;
#pragma unroll
            for (int f = 0; f < 4; ++f) {
                o[f][0] *= alpha; o[f][1] *= alpha; o[f][2] *= alpha; o[f][3] *= alpha;
            }

            // ---- pack P -> bf16 (truncation), same-wave LDS round trip ----
#pragma unroll
            for (int kg = 0; kg < 4; ++kg) {
                const unsigned int b0 = __builtin_bit_cast(unsigned int, p[kg * 4 + 0]);
                const unsigned int b1 = __builtin_bit_cast(unsigned int, p[kg * 4 + 1]);
                const unsigned int b2 = __builtin_bit_cast(unsigned int, p[kg * 4 + 2]);
                const unsigned int b3 = __builtin_bit_cast(unsigned int, p[kg * 4 + 3]);
                uint2 pk;
                pk.x = (b0 >> 16) | (b1 & 0xffff0000u);
                pk.y = (b2 >> 16) | (b3 & 0xffff0000u);
                *(uint2*)&Ps[w][n][kg * 16 + quad * 4] = pk;
            }
            const short8_t pb0 = *(const short8_t*)&Ps[w][n][quad * 8];
            const short8_t pb1 = *(const short8_t*)&Ps[w][n][quad * 8 + 32];

            // ---- O^T += V^T_tile . P^T ----
#pragma unroll
            for (int f = 0; f < 4; ++f) {
                const int rbase = cur + (f * 16 + n) * 64;
                const short8_t va0 = *(const short8_t*)&Vs[rbase + pcK];
                const short8_t va1 = *(const short8_t*)&Vs[rbase + (pcK ^ 32)];
                o[f] = __builtin_amdgcn_mfma_f32_16x16x32_bf16(va0, pb0, o[f], 0, 0, 0);
                o[f] = __builtin_amdgcn_mfma_f32_16x16x32_bf16(va1, pb1, o[f], 0, 0, 0);
            }
        }

        // ---- epilogue: swizzled transpose through Ks/Vs buffer 0 regions ----
        __syncthreads();   // all waves done reading K/V buffers this pass
        float* Os = (float*)((w < 2) ? Ks : Vs) + (w & 1) * 1024;  // 16x64 floats
        const float inv_l = 1.0f / l;
#pragma unroll
        for (int f = 0; f < 4; ++f) {
            const int c  = f * 4 + quad;          // logical 16B chunk (dh/4)
            const int pc = c ^ n;                 // physical chunk
            f32x4 q4;
            q4[0] = o[f][0] * inv_l; q4[1] = o[f][1] * inv_l;
            q4[2] = o[f][2] * inv_l; q4[3] = o[f][3] * inv_l;
            *(f32x4*)&Os[n * 64 + pc * 4] = q4;   // row n, dh chunk c
        }
#pragma unroll
        for (int rr = 0; rr < 4; ++rr) {
            const int row = rr * 4 + quad;        // q-row within wave tile
            const int pc  = n ^ row;              // logical chunk n, swizzled
            const f32x4 val = *(const f32x4*)&Os[row * 64 + pc * 4];
            *(f32x4*)(out + ((size_t)(bb * S_LEN + r0 + row)) * D_MODEL
                          + hh * D_HEAD + n * 4) = val;
        }
    }
}

// ---------------------------------------------------------------------------
extern "C" void kernel_launch(void* const* d_in, const int* in_sizes, int n_in,
                              void* d_out, int out_size, void* d_ws, size_t ws_size,
                              hipStream_t stream) {
    const float* x  = (const float*)d_in[0];
    const float* Wq = (const float*)d_in[1];
    const float* Wk = (const float*)d_in[2];
    const float* Wv = (const float*)d_in[3];
    float* out = (float*)d_out;

    // workspace: xb (8MB) | wt (6MB) | qkv (24MB) = 38MB
    short* xb  = (short*)d_ws;
    short* wt  = xb + MAT_ELEMS;
    short* qkv = wt + 3 * W_ELEMS;

    convert_x_kernel<<<dim3(MAT_ELEMS / (256 * 8)), 256, 0, stream>>>(x, xb);
    transpose_w_kernel<<<dim3(16, 16, 3), 256, 0, stream>>>(Wq, Wk, Wv, wt);

    qkv_mfma_gemm_kernel<<<dim3(32, 8, 3), 256, 0, stream>>>(xb, wt, qkv);

    attn_mfma_kernel<<<dim3(2 * N_HEADS, 16), 256, 0, stream>>>(qkv, out);
}

// Round 9
// 154.381 us; speedup vs baseline: 1.3535x; 1.0389x over previous
//
#include <hip/hip_runtime.h>
#include <hip/hip_bf16.h>

// B=2, S=2048, D=1024, H=16, DH=64. fp32 in/out; bf16 MFMA internals.
#define S_LEN   2048
#define D_MODEL 1024
#define N_HEADS 16
#define D_HEAD  64
#define HEAD_ELEMS (2048ull * 64ull)          // elements per (b,h) plane
#define MAT_ELEMS  (4096ull * 1024ull)        // one projected matrix (Q/K/V)
#define W_ELEMS    (1024ull * 1024ull)        // one weight matrix

typedef __attribute__((ext_vector_type(8))) short short8_t;   // 8 bf16
typedef __attribute__((ext_vector_type(4))) short short4_t;   // 4 bf16
typedef __attribute__((ext_vector_type(4))) float f32x4;      // MFMA C/D frag

__device__ __forceinline__ short f2bf(float f) {
    __hip_bfloat16 h = __float2bfloat16(f);
    union { __hip_bfloat16 h; short s; } cv;
    cv.h = h;
    return cv.s;
}

// global_load_lds width=16: LDS dest = wave-uniform base + lane*16
#define GLD_LDS16(gptr, lptr) \
    __builtin_amdgcn_global_load_lds( \
        (const __attribute__((address_space(1))) unsigned int*)(gptr), \
        (__attribute__((address_space(3))) unsigned int*)(lptr), 16, 0, 0)

// ---------------------------------------------------------------------------
// Kernel 0: fused prep. Blocks [0,2048): convert x fp32->bf16.
// Blocks [2048,2816): convert+transpose W fp32[k][n] -> bf16 Wt[n][k].
// ---------------------------------------------------------------------------
__global__ __launch_bounds__(256) void prep_kernel(
    const float* __restrict__ x,
    const float* __restrict__ Wq, const float* __restrict__ Wk,
    const float* __restrict__ Wv,
    short* __restrict__ xb, short* __restrict__ wt)
{
    __shared__ float Ts[64][68];   // [n_local][k_local] (transpose part only)
    const int t = threadIdx.x;
    const int id = blockIdx.x;
    if (id < 2048) {
        const int i = (id * 256 + t) * 8;
        const float4 v0 = *(const float4*)(x + i);
        const float4 v1 = *(const float4*)(x + i + 4);
        short8_t u;
        u[0] = f2bf(v0.x); u[1] = f2bf(v0.y); u[2] = f2bf(v0.z); u[3] = f2bf(v0.w);
        u[4] = f2bf(v1.x); u[5] = f2bf(v1.y); u[6] = f2bf(v1.z); u[7] = f2bf(v1.w);
        *(short8_t*)(xb + i) = u;
        return;
    }
    const int id2   = id - 2048;           // 0..767
    const int which = id2 >> 8;
    const int rem   = id2 & 255;
    const int k0 = (rem & 15) * 64;
    const int n0 = (rem >> 4) * 64;
    const float* W = (which == 0) ? Wq : (which == 1) ? Wk : Wv;
    short* out = wt + (size_t)which * W_ELEMS;
    {
        const int c4 = (t & 15) * 4;
#pragma unroll
        for (int i = 0; i < 4; ++i) {
            const int r = (t >> 4) + i * 16;
            const float4 v = *(const float4*)(W + (size_t)(k0 + r) * D_MODEL + n0 + c4);
            Ts[c4 + 0][r] = v.x; Ts[c4 + 1][r] = v.y;
            Ts[c4 + 2][r] = v.z; Ts[c4 + 3][r] = v.w;
        }
    }
    __syncthreads();
    const int nl = t >> 2;
#pragma unroll
    for (int s = 0; s < 2; ++s) {
        const int koff = (t & 3) * 8 + s * 32;
        short8_t u;
#pragma unroll
        for (int j = 0; j < 8; ++j) u[j] = f2bf(Ts[nl][koff + j]);
        *(short8_t*)(out + (size_t)(n0 + nl) * D_MODEL + k0 + koff) = u;
    }
}

// ---------------------------------------------------------------------------
// Kernel 1: QKV GEMM, m97 structure (round-5 epilogue; Q folds 0.125*log2e).
// ---------------------------------------------------------------------------
__global__ __launch_bounds__(256, 3) void qkv_mfma_gemm_kernel(
    const short* __restrict__ xb,
    const short* __restrict__ wt,
    short* __restrict__ qkv)
{
    const int mBlock = blockIdx.x * 128;
    const int nBlock = blockIdx.y * 128;
    const int which  = blockIdx.z;
    const short* Bt = wt + (size_t)which * W_ELEMS;
    short* outBase  = qkv + (size_t)which * MAT_ELEMS;

    __shared__ short As[128 * 32];   // [m][k] contiguous, 8 KB
    __shared__ short Bs[128 * 32];   // [n][k] contiguous, 8 KB

    const int t    = threadIdx.x;
    const int w    = t >> 6;
    const int lane = t & 63;
    const int n16  = lane & 15;
    const int quad = lane >> 4;
    const int mq   = (w & 1) * 64;
    const int nq   = (w >> 1) * 64;

    f32x4 acc[4][4];
#pragma unroll
    for (int i = 0; i < 4; ++i)
#pragma unroll
        for (int j = 0; j < 4; ++j) acc[i][j] = (f32x4){0.f, 0.f, 0.f, 0.f};

    const int off0 = w * 2048 + lane * 16;       // bytes
    const int off1 = off0 + 1024;
    const int r0s = off0 >> 6, k0s = (off0 & 63) >> 1;
    const int r1s = off1 >> 6, k1s = (off1 & 63) >> 1;
    const short* gA0 = xb + (size_t)(mBlock + r0s) * D_MODEL + k0s;
    const short* gA1 = xb + (size_t)(mBlock + r1s) * D_MODEL + k1s;
    const short* gB0 = Bt + (size_t)(nBlock + r0s) * D_MODEL + k0s;
    const short* gB1 = Bt + (size_t)(nBlock + r1s) * D_MODEL + k1s;
    short* lA0 = As + w * 1024;
    short* lA1 = As + w * 1024 + 512;
    short* lB0 = Bs + w * 1024;
    short* lB1 = Bs + w * 1024 + 512;

    for (int k0 = 0; k0 < D_MODEL; k0 += 32) {
        __syncthreads();
        GLD_LDS16(gA0 + k0, lA0);
        GLD_LDS16(gA1 + k0, lA1);
        GLD_LDS16(gB0 + k0, lB0);
        GLD_LDS16(gB1 + k0, lB1);
        __syncthreads();

        short8_t af[4], bf[4];
#pragma unroll
        for (int mt = 0; mt < 4; ++mt)
            af[mt] = *(const short8_t*)&As[(mq + mt * 16 + n16) * 32 + quad * 8];
#pragma unroll
        for (int nt = 0; nt < 4; ++nt)
            bf[nt] = *(const short8_t*)&Bs[(nq + nt * 16 + n16) * 32 + quad * 8];
#pragma unroll
        for (int mt = 0; mt < 4; ++mt)
#pragma unroll
            for (int nt = 0; nt < 4; ++nt)
                acc[mt][nt] = __builtin_amdgcn_mfma_f32_16x16x32_bf16(
                    af[mt], bf[nt], acc[mt][nt], 0, 0, 0);
    }

    // Q scale: 1/sqrt(64) * log2(e) so softmax uses raw v_exp_f32 (exp2).
    const float oscale = (which == 0) ? 0.18033688f : 1.0f;
    if (which < 2) {
#pragma unroll
        for (int mt = 0; mt < 4; ++mt) {
#pragma unroll
            for (int nt = 0; nt < 4; ++nt) {
                const int n = nBlock + nq + nt * 16 + n16;
                const int h = n >> 6, dh = n & 63;
#pragma unroll
                for (int reg = 0; reg < 4; ++reg) {
                    const int m = mBlock + mq + mt * 16 + quad * 4 + reg;
                    const int bb = m >> 11, ss = m & 2047;
                    outBase[((size_t)(bb * N_HEADS + h) * S_LEN + ss) * D_HEAD + dh] =
                        f2bf(acc[mt][nt][reg] * oscale);
                }
            }
        }
    } else {
        // V transposed (b,h,dh,s): regs = 4 consecutive s -> one 8B store
#pragma unroll
        for (int mt = 0; mt < 4; ++mt) {
            const int m0 = mBlock + mq + mt * 16 + quad * 4;
            const int bb = m0 >> 11, ss0 = m0 & 2047;
#pragma unroll
            for (int nt = 0; nt < 4; ++nt) {
                const int n = nBlock + nq + nt * 16 + n16;
                const int h = n >> 6, dh = n & 63;
                short4_t u;
                u[0] = f2bf(acc[mt][nt][0]); u[1] = f2bf(acc[mt][nt][1]);
                u[2] = f2bf(acc[mt][nt][2]); u[3] = f2bf(acc[mt][nt][3]);
                *(short4_t*)(outBase +
                    ((size_t)((bb * N_HEADS + h) * D_HEAD + dh)) * S_LEN + ss0) = u;
            }
        }
    }
}

// ---------------------------------------------------------------------------
// Kernel 2: causal flash attention via bf16 MFMA — exact round-5 structure
// (measured 48.1 us), with __expf replaced by __builtin_amdgcn_exp2f
// (raw v_exp_f32; log2e folded into Q by the GEMM epilogue).
// grid (bh=32, pair=16): block handles q-tiles {p, 31-p} -> uniform 33 tiles.
// ---------------------------------------------------------------------------
__global__ __launch_bounds__(256, 2) void attn_mfma_kernel(
    const short* __restrict__ qkv,
    float* __restrict__ out)
{
    const int bh   = blockIdx.x;
    const int pr   = blockIdx.y;          // pair index 0..15
    const int t    = threadIdx.x;
    const int w    = t >> 6;
    const int lane = t & 63;
    const int n    = lane & 15;
    const int quad = lane >> 4;

    const short* Q  = qkv + (size_t)bh * HEAD_ELEMS;
    const short* K  = qkv + MAT_ELEMS + (size_t)bh * HEAD_ELEMS;
    const short* Vt = qkv + 2 * MAT_ELEMS + (size_t)bh * HEAD_ELEMS;  // (dh,s)

    __shared__ __align__(16) short Ks[64 * 64];          // swizzled [row][chunk]
    __shared__ __align__(16) short Vs[64 * 64];          // swizzled [dh][chunk]
    __shared__ __align__(16) short Ps[4][16][72];        // per-wave P round-trip

    // --- staging: wave w stages rows [16w,16w+16) of K and V, 2 insts each ---
    const int srow0 = w * 16 + (lane >> 3);
    const int srow1 = srow0 + 8;
    const int sd0 = ((lane & 7) ^ (srow0 & 7)) * 8;      // swizzled src offset
    const int sd1 = ((lane & 7) ^ (srow1 & 7)) * 8;
    const short* gK0 = K + srow0 * 64 + sd0;
    const short* gK1 = K + srow1 * 64 + sd1;
    const short* gV0 = Vt + (size_t)srow0 * S_LEN + sd0;
    const short* gV1 = Vt + (size_t)srow1 * S_LEN + sd1;
    short* lK0 = Ks + (w * 16) * 64;
    short* lK1 = Ks + (w * 16 + 8) * 64;
    short* lV0 = Vs + (w * 16) * 64;
    short* lV1 = Vs + (w * 16 + 8) * 64;

    // frag-read physical chunk offset (shorts): a0 at pcK, a1 at pcK^32
    const int pcK = (quad ^ (n & 7)) * 8;

    const int bb = bh >> 4;
    const int hh = bh & 15;

    for (int pass = 0; pass < 2; ++pass) {
        const int qb = pass ? (31 - pr) : pr;
        const int r0 = qb * 64 + w * 16;
        const int qrow = r0 + n;

        const short8_t bq0 = *(const short8_t*)(Q + (size_t)qrow * D_HEAD + quad * 8);
        const short8_t bq1 = *(const short8_t*)(Q + (size_t)qrow * D_HEAD + quad * 8 + 32);

        float m = -__builtin_inff();
        float l = 0.f;
        f32x4 o[4];
#pragma unroll
        for (int f = 0; f < 4; ++f) o[f] = (f32x4){0.f, 0.f, 0.f, 0.f};

        for (int tile = 0; tile <= qb; ++tile) {
            const int j0 = tile * 64;
            __syncthreads();                       // prior LDS reads done
            GLD_LDS16(gK0 + j0 * 64, lK0);
            GLD_LDS16(gK1 + j0 * 64, lK1);
            GLD_LDS16(gV0 + j0, lV0);
            GLD_LDS16(gV1 + j0, lV1);
            __syncthreads();                       // vmcnt drained by barrier

            // ---- S^T = K_tile . Q^T (Q pre-scaled by 0.125*log2e) ----
            f32x4 st[4];
#pragma unroll
            for (int kg = 0; kg < 4; ++kg) {
                const int rbase = (kg * 16 + n) * 64;
                const short8_t a0 = *(const short8_t*)&Ks[rbase + pcK];
                const short8_t a1 = *(const short8_t*)&Ks[rbase + (pcK ^ 32)];
                f32x4 acc = (f32x4){0.f, 0.f, 0.f, 0.f};
                acc = __builtin_amdgcn_mfma_f32_16x16x32_bf16(a0, bq0, acc, 0, 0, 0);
                acc = __builtin_amdgcn_mfma_f32_16x16x32_bf16(a1, bq1, acc, 0, 0, 0);
                st[kg] = acc;
            }

            // ---- online softmax, exp2 domain (mask only on diagonal) ----
            float p[16];
            float mx = -__builtin_inff();
            if (tile == qb) {
#pragma unroll
                for (int kg = 0; kg < 4; ++kg)
#pragma unroll
                    for (int r = 0; r < 4; ++r) {
                        const int key = j0 + kg * 16 + quad * 4 + r;
                        float s = st[kg][r];
                        s = (key <= qrow) ? s : -__builtin_inff();
                        p[kg * 4 + r] = s;
                        mx = fmaxf(mx, s);
                    }
            } else {
#pragma unroll
                for (int i = 0; i < 16; ++i) {
                    const float s = st[i >> 2][i & 3];
                    p[i] = s;
                    mx = fmaxf(mx, s);
                }
            }
            mx = fmaxf(mx, __shfl_xor(mx, 16));
            mx = fmaxf(mx, __shfl_xor(mx, 32));
            const float mnew  = fmaxf(m, mx);
            const float alpha = __builtin_amdgcn_exp2f(m - mnew);
            float ls = 0.f;
#pragma unroll
            for (int i = 0; i < 16; ++i) {
                p[i] = __builtin_amdgcn_exp2f(p[i] - mnew);
                ls += p[i];
            }
            ls += __shfl_xor(ls, 16);
            ls += __shfl_xor(ls, 32);
            l = l * alpha + ls;
            m = mnew;
#pragma unroll
            for (int f = 0; f < 4; ++f) {
                o[f][0] *= alpha; o[f][1] *= alpha; o[f][2] *= alpha; o[f][3] *= alpha;
            }

            // ---- pack P -> bf16 (truncation), same-wave LDS round trip ----
#pragma unroll
            for (int kg = 0; kg < 4; ++kg) {
                const unsigned int b0 = __builtin_bit_cast(unsigned int, p[kg * 4 + 0]);
                const unsigned int b1 = __builtin_bit_cast(unsigned int, p[kg * 4 + 1]);
                const unsigned int b2 = __builtin_bit_cast(unsigned int, p[kg * 4 + 2]);
                const unsigned int b3 = __builtin_bit_cast(unsigned int, p[kg * 4 + 3]);
                uint2 pk;
                pk.x = (b0 >> 16) | (b1 & 0xffff0000u);
                pk.y = (b2 >> 16) | (b3 & 0xffff0000u);
                *(uint2*)&Ps[w][n][kg * 16 + quad * 4] = pk;
            }
            const short8_t pb0 = *(const short8_t*)&Ps[w][n][quad * 8];
            const short8_t pb1 = *(const short8_t*)&Ps[w][n][quad * 8 + 32];

            // ---- O^T += V^T_tile . P^T ----
#pragma unroll
            for (int f = 0; f < 4; ++f) {
                const int rbase = (f * 16 + n) * 64;
                const short8_t va0 = *(const short8_t*)&Vs[rbase + pcK];
                const short8_t va1 = *(const short8_t*)&Vs[rbase + (pcK ^ 32)];
                o[f] = __builtin_amdgcn_mfma_f32_16x16x32_bf16(va0, pb0, o[f], 0, 0, 0);
                o[f] = __builtin_amdgcn_mfma_f32_16x16x32_bf16(va1, pb1, o[f], 0, 0, 0);
            }
        }

        // ---- epilogue: swizzled transpose through Ks/Vs, coalesced stores ----
        __syncthreads();   // all waves done reading Ks/Vs this pass
        float* Os = (float*)((w < 2) ? Ks : Vs) + (w & 1) * 1024;  // 16x64 floats
        const float inv_l = 1.0f / l;
#pragma unroll
        for (int f = 0; f < 4; ++f) {
            const int c  = f * 4 + quad;          // logical 16B chunk (dh/4)
            const int pc = c ^ n;                 // physical chunk
            f32x4 q4;
            q4[0] = o[f][0] * inv_l; q4[1] = o[f][1] * inv_l;
            q4[2] = o[f][2] * inv_l; q4[3] = o[f][3] * inv_l;
            *(f32x4*)&Os[n * 64 + pc * 4] = q4;   // row n, dh chunk c
        }
#pragma unroll
        for (int rr = 0; rr < 4; ++rr) {
            const int row = rr * 4 + quad;        // q-row within wave tile
            const int pc  = n ^ row;              // logical chunk n, swizzled
            const f32x4 val = *(const f32x4*)&Os[row * 64 + pc * 4];
            *(f32x4*)(out + ((size_t)(bb * S_LEN + r0 + row)) * D_MODEL
                          + hh * D_HEAD + n * 4) = val;
        }
        // next pass's first tile starts with __syncthreads -> safe to restage
    }
}

// ---------------------------------------------------------------------------
extern "C" void kernel_launch(void* const* d_in, const int* in_sizes, int n_in,
                              void* d_out, int out_size, void* d_ws, size_t ws_size,
                              hipStream_t stream) {
    const float* x  = (const float*)d_in[0];
    const float* Wq = (const float*)d_in[1];
    const float* Wk = (const float*)d_in[2];
    const float* Wv = (const float*)d_in[3];
    float* out = (float*)d_out;

    // workspace: xb (8MB) | wt (6MB) | qkv (24MB) = 38MB
    short* xb  = (short*)d_ws;
    short* wt  = xb + MAT_ELEMS;
    short* qkv = wt + 3 * W_ELEMS;

    prep_kernel<<<dim3(2048 + 768), 256, 0, stream>>>(x, Wq, Wk, Wv, xb, wt);

    qkv_mfma_gemm_kernel<<<dim3(32, 8, 3), 256, 0, stream>>>(xb, wt, qkv);

    attn_mfma_kernel<<<dim3(2 * N_HEADS, 16), 256, 0, stream>>>(qkv, out);
}